// Round 1
// baseline (806.630 us; speedup 1.0000x reference)
//
#include <hip/hip_runtime.h>
#include <hip/hip_bf16.h>

typedef __bf16 bf16_t;
typedef __attribute__((ext_vector_type(8))) __bf16 bf16x8;
typedef __attribute__((ext_vector_type(4))) __bf16 bf16x4;
typedef __attribute__((ext_vector_type(4))) float f32x4;

#define NPOS 38416  // 196*196
#define NPAD 224    // 7*32

// ---------------- cast x -> bf16 ----------------
__global__ __launch_bounds__(256) void cast_x_kernel(const float* __restrict__ x,
                                                     bf16_t* __restrict__ xb, int n4) {
  int i = blockIdx.x * 256 + threadIdx.x;
  if (i < n4) {
    float4 v = ((const float4*)x)[i];
    bf16x4 o;
    o[0] = (bf16_t)v.x; o[1] = (bf16_t)v.y; o[2] = (bf16_t)v.z; o[3] = (bf16_t)v.w;
    ((bf16x4*)xb)[i] = o;
  }
}

// ---------------- transpose + cast W: src[K][Ncols] f32 -> dst[Ncols][K] bf16 ----------------
__global__ __launch_bounds__(256) void transpose_cast_kernel(const float* __restrict__ src,
                                                             bf16_t* __restrict__ dst,
                                                             int K, int Ncols) {
  __shared__ float tile[32][33];
  int t = threadIdx.x;
  int tx = t & 31, ty = t >> 5;
  int bx = blockIdx.x, by = blockIdx.y;
  for (int r = ty; r < 32; r += 8)
    tile[r][tx] = src[(size_t)(by * 32 + r) * Ncols + bx * 32 + tx];
  __syncthreads();
  for (int r = ty; r < 32; r += 8)
    dst[(size_t)(bx * 32 + r) * K + by * 32 + tx] = (bf16_t)tile[tx][r];
}

// ---------------- bias gather: bias[h][i*196+j] = rpk[rel_idx[i][j]][h] ----------------
__global__ __launch_bounds__(256) void bias_gather_kernel(const float* __restrict__ rpk,
                                                          const int* __restrict__ rel_idx,
                                                          float* __restrict__ bias) {
  int pos = blockIdx.x * 256 + threadIdx.x;
  if (pos < NPOS) {
    int idx = rel_idx[pos];
    const float* r = rpk + idx * 32;
#pragma unroll
    for (int h = 0; h < 32; ++h) bias[h * NPOS + pos] = r[h];
  }
}

// ---------------- 128x128 bf16 GEMM, B^T input, K=1024 ----------------
// MODE 0: epilogue scatters qkv -> q [B,H,N,HD] (scaled), k [B,H,N,HD], vT [B,H,HD,N]
// MODE 1: epilogue writes fp32 out + b_proj
template <int MODE>
__global__ __launch_bounds__(256, 2) void gemm_bt_kernel(
    const bf16_t* __restrict__ A, const bf16_t* __restrict__ Bt,
    bf16_t* __restrict__ qo, bf16_t* __restrict__ ko, bf16_t* __restrict__ vto,
    float* __restrict__ fo, const float* __restrict__ bp) {
  constexpr int K = 1024;
  __shared__ alignas(16) bf16_t As[128 * 32];
  __shared__ alignas(16) bf16_t Bs[128 * 32];
  const int t = threadIdx.x;
  const int lane = t & 63;
  const int quad = lane >> 4;
  const int l16 = lane & 15;
  const int wave = t >> 6;
  const int m0 = blockIdx.x * 128, n0 = blockIdx.y * 128;
  const int wr = (wave >> 1) * 64, wc = (wave & 1) * 64;

  const int c0 = t, c1 = t + 256;
  const bf16_t* gA0 = A + (size_t)(m0 + (c0 >> 2)) * K + (c0 & 3) * 8;
  const bf16_t* gA1 = A + (size_t)(m0 + (c1 >> 2)) * K + (c1 & 3) * 8;
  const bf16_t* gB0 = Bt + (size_t)(n0 + (c0 >> 2)) * K + (c0 & 3) * 8;
  const bf16_t* gB1 = Bt + (size_t)(n0 + (c1 >> 2)) * K + (c1 & 3) * 8;

  const f32x4 vzero = {0.f, 0.f, 0.f, 0.f};
  f32x4 acc[4][4];
#pragma unroll
  for (int i = 0; i < 4; ++i)
#pragma unroll
    for (int j = 0; j < 4; ++j) acc[i][j] = vzero;

  for (int kt = 0; kt < K; kt += 32) {
    uint4 ra0 = *(const uint4*)(gA0 + kt);
    uint4 ra1 = *(const uint4*)(gA1 + kt);
    uint4 rb0 = *(const uint4*)(gB0 + kt);
    uint4 rb1 = *(const uint4*)(gB1 + kt);
    __syncthreads();
    *(uint4*)(As + c0 * 8) = ra0;
    *(uint4*)(As + c1 * 8) = ra1;
    *(uint4*)(Bs + c0 * 8) = rb0;
    *(uint4*)(Bs + c1 * 8) = rb1;
    __syncthreads();
    bf16x8 af[4], bfr[4];
#pragma unroll
    for (int i = 0; i < 4; ++i) {
      af[i] = *(const bf16x8*)(As + (wr + i * 16 + l16) * 32 + quad * 8);
      bfr[i] = *(const bf16x8*)(Bs + (wc + i * 16 + l16) * 32 + quad * 8);
    }
#pragma unroll
    for (int i = 0; i < 4; ++i)
#pragma unroll
      for (int j = 0; j < 4; ++j)
        acc[i][j] = __builtin_amdgcn_mfma_f32_16x16x32_bf16(af[i], bfr[j], acc[i][j], 0, 0, 0);
  }

  if (MODE == 0) {
    const float qscale = 0.17677669529663687f;  // 1/sqrt(32)
    const int which = n0 >> 10;                 // uniform per block (1024 % 128 == 0)
#pragma unroll
    for (int i = 0; i < 4; ++i) {
      const int rb = m0 + wr + i * 16 + quad * 4;
#pragma unroll
      for (int j = 0; j < 4; ++j) {
        const int c = n0 + wc + j * 16 + l16;
        const int h = (c >> 5) & 31, d = c & 31;
#pragma unroll
        for (int r = 0; r < 4; ++r) {
          const int rg = rb + r;
          const int b = rg / 196, n = rg - b * 196;
          const float v = acc[i][j][r];
          if (which == 0)
            qo[(((size_t)b * 32 + h) * 196 + n) * 32 + d] = (bf16_t)(v * qscale);
          else if (which == 1)
            ko[(((size_t)b * 32 + h) * 196 + n) * 32 + d] = (bf16_t)v;
          else
            vto[(((size_t)b * 32 + h) * 32 + d) * 196 + n] = (bf16_t)v;
        }
      }
    }
  } else {
#pragma unroll
    for (int i = 0; i < 4; ++i) {
      const int rb = m0 + wr + i * 16 + quad * 4;
#pragma unroll
      for (int j = 0; j < 4; ++j) {
        const int c = n0 + wc + j * 16 + l16;
        const float bias_c = bp[c];
#pragma unroll
        for (int r = 0; r < 4; ++r)
          fo[(size_t)(rb + r) * 1024 + c] = acc[i][j][r] + bias_c;
      }
    }
  }
}

// ---------------- attention: one block per (b,h) ----------------
__global__ __launch_bounds__(256, 2) void attn_kernel(
    const bf16_t* __restrict__ q, const bf16_t* __restrict__ kmat,
    const bf16_t* __restrict__ vtg, const float* __restrict__ bias,
    bf16_t* __restrict__ attn_out) {
  __shared__ alignas(16) bf16_t kf[NPAD * 32];   // K rows [n][d], rows >=196 zero
  __shared__ alignas(16) bf16_t vts[32 * NPAD];  // V^T [d][n], cols >=196 zero
  __shared__ alignas(16) float sc[32 * 228];     // score chunk, stride 228 (bank spread)
  __shared__ alignas(16) bf16_t pb[32 * NPAD];   // unnormalized probs (bf16)
  __shared__ float inv_s[32];

  const int t = threadIdx.x;
  const int lane = t & 63;
  const int quad = lane >> 4, l16 = lane & 15;
  const int wave = t >> 6;
  const int bh = blockIdx.x;
  const int b = bh >> 5, h = bh & 31;
  const bf16_t* qg = q + (size_t)bh * (196 * 32);
  const bf16_t* kg = kmat + (size_t)bh * (196 * 32);
  const bf16_t* vg = vtg + (size_t)bh * (32 * 196);
  const float* bg = bias + (size_t)h * NPOS;

  {
    const uint4* src = (const uint4*)kg;
    uint4* dst = (uint4*)kf;
    for (int c = t; c < 784; c += 256) dst[c] = src[c];
    const uint4 z = {0u, 0u, 0u, 0u};
    for (int c = 784 + t; c < 896; c += 256) dst[c] = z;
    const unsigned short* vsrc = (const unsigned short*)vg;
    unsigned short* vdst = (unsigned short*)vts;
    for (int i = t; i < 32 * NPAD; i += 256) {
      int d = i / NPAD, n = i - d * NPAD;
      vdst[i] = (n < 196) ? vsrc[d * 196 + n] : (unsigned short)0;
    }
  }
  __syncthreads();

  const f32x4 vzero = {0.f, 0.f, 0.f, 0.f};
  for (int ch = 0; ch < 7; ++ch) {
    const int q0 = ch * 32;
    bf16x8 aq[2];
#pragma unroll
    for (int rt = 0; rt < 2; ++rt) {
      int row = q0 + rt * 16 + l16;
      if (row > 195) row = 195;  // clamp (rows >=196 are discarded later)
      aq[rt] = *(const bf16x8*)(qg + row * 32 + quad * 8);
    }
    // scores: 2x14 tiles of 16x16, round-robin over 4 waves
    for (int ti = wave; ti < 28; ti += 4) {
      const int rt = ti / 14, ct = ti - rt * 14;
      const bf16x8 bk = *(const bf16x8*)(kf + (ct * 16 + l16) * 32 + quad * 8);
      f32x4 s = __builtin_amdgcn_mfma_f32_16x16x32_bf16(aq[rt], bk, vzero, 0, 0, 0);
      const int col = ct * 16 + l16;
#pragma unroll
      for (int r = 0; r < 4; ++r) {
        const int rowc = rt * 16 + quad * 4 + r;
        float v;
        if (col < 196) {
          int br = q0 + rowc;
          if (br > 195) br = 195;
          v = s[r] + bg[br * 196 + col];
        } else {
          v = -1e30f;
        }
        sc[rowc * 228 + col] = v;
      }
    }
    __syncthreads();
    // softmax: 8 lanes per row, unnormalized exp -> pb (bf16), 1/sum -> inv_s
    {
      const int row = t >> 3, c8 = t & 7;
      float m = -1e30f;
      for (int j = c8; j < NPAD; j += 8) m = fmaxf(m, sc[row * 228 + j]);
      m = fmaxf(m, __shfl_xor(m, 1));
      m = fmaxf(m, __shfl_xor(m, 2));
      m = fmaxf(m, __shfl_xor(m, 4));
      float ssum = 0.f;
      for (int j = c8; j < NPAD; j += 8) {
        const float e = __expf(sc[row * 228 + j] - m);
        ssum += e;
        pb[row * NPAD + j] = (bf16_t)e;
      }
      ssum += __shfl_xor(ssum, 1);
      ssum += __shfl_xor(ssum, 2);
      ssum += __shfl_xor(ssum, 4);
      if (c8 == 0) inv_s[row] = 1.f / ssum;
    }
    __syncthreads();
    // PV: 4 tiles of 16x16 (2 row-tiles x 2 d-tiles), one per wave; K-dim = 224
    {
      const int rt = wave >> 1, dt = wave & 1;
      f32x4 o = vzero;
#pragma unroll
      for (int kk = 0; kk < 7; ++kk) {
        const bf16x8 ap = *(const bf16x8*)(pb + (rt * 16 + l16) * NPAD + kk * 32 + quad * 8);
        const bf16x8 bv = *(const bf16x8*)(vts + (dt * 16 + l16) * NPAD + kk * 32 + quad * 8);
        o = __builtin_amdgcn_mfma_f32_16x16x32_bf16(ap, bv, o, 0, 0, 0);
      }
      const int d = dt * 16 + l16;
#pragma unroll
      for (int r = 0; r < 4; ++r) {
        const int rowc = rt * 16 + quad * 4 + r;
        const int n = q0 + rowc;
        if (n < 196)
          attn_out[(((size_t)b * 196 + n) * 32 + h) * 32 + d] = (bf16_t)(o[r] * inv_s[rowc]);
      }
    }
    __syncthreads();
  }
}

extern "C" void kernel_launch(void* const* d_in, const int* in_sizes, int n_in,
                              void* d_out, int out_size, void* d_ws, size_t ws_size,
                              hipStream_t stream) {
  (void)in_sizes; (void)n_in; (void)out_size; (void)ws_size;
  const float* x = (const float*)d_in[0];
  const float* Wqkv = (const float*)d_in[1];
  const float* Wproj = (const float*)d_in[2];
  const float* bproj = (const float*)d_in[3];
  const float* rpk = (const float*)d_in[4];
  const int* rel_idx = (const int*)d_in[5];
  float* out = (float*)d_out;

  char* ws = (char*)d_ws;
  bf16_t* xb = (bf16_t*)(ws + 0);                  // 25,690,112 B ; reused as attn_out
  bf16_t* wqkvT = (bf16_t*)(ws + 25690112);        //  6,291,456 B
  bf16_t* wprojT = (bf16_t*)(ws + 31981568);       //  2,097,152 B
  bf16_t* q = (bf16_t*)(ws + 34078720);            // 25,690,112 B
  bf16_t* kk = (bf16_t*)(ws + 59768832);           // 25,690,112 B
  bf16_t* vt = (bf16_t*)(ws + 85458944);           // 25,690,112 B
  float* bias = (float*)(ws + 111149056);          //  4,917,248 B  (total ~116 MB)
  bf16_t* attn = xb;                               // xb is dead after GEMM1

  cast_x_kernel<<<12544, 256, 0, stream>>>(x, xb, 12845056 / 4);
  transpose_cast_kernel<<<dim3(96, 32), 256, 0, stream>>>(Wqkv, wqkvT, 1024, 3072);
  transpose_cast_kernel<<<dim3(32, 32), 256, 0, stream>>>(Wproj, wprojT, 1024, 1024);
  bias_gather_kernel<<<151, 256, 0, stream>>>(rpk, rel_idx, bias);
  gemm_bt_kernel<0><<<dim3(98, 24), 256, 0, stream>>>(xb, wqkvT, q, kk, vt, nullptr, nullptr);
  attn_kernel<<<2048, 256, 0, stream>>>(q, kk, vt, bias, attn);
  gemm_bt_kernel<1><<<dim3(98, 8), 256, 0, stream>>>(attn, wprojT, nullptr, nullptr, nullptr, out, bproj);
}

// Round 2
// 375.040 us; speedup vs baseline: 2.1508x; 2.1508x over previous
//
#include <hip/hip_runtime.h>
#include <hip/hip_bf16.h>

typedef __bf16 bf16_t;
typedef __attribute__((ext_vector_type(8))) __bf16 bf16x8;
typedef __attribute__((ext_vector_type(4))) __bf16 bf16x4;
typedef __attribute__((ext_vector_type(4))) float f32x4;

#define NPOS 38416  // 196*196
#define NPAD 224    // 7*32

__device__ __forceinline__ void async_copy16(const bf16_t* g, bf16_t* l) {
  __builtin_amdgcn_global_load_lds((const __attribute__((address_space(1))) void*)g,
                                   (__attribute__((address_space(3))) void*)l, 16, 0, 0);
}

// ---------------- cast x -> bf16 ----------------
__global__ __launch_bounds__(256) void cast_x_kernel(const float* __restrict__ x,
                                                     bf16_t* __restrict__ xb, int n4) {
  int i = blockIdx.x * 256 + threadIdx.x;
  if (i < n4) {
    float4 v = ((const float4*)x)[i];
    bf16x4 o;
    o[0] = (bf16_t)v.x; o[1] = (bf16_t)v.y; o[2] = (bf16_t)v.z; o[3] = (bf16_t)v.w;
    ((bf16x4*)xb)[i] = o;
  }
}

// ---------------- transpose + cast W: src[K][Ncols] f32 -> dst[Ncols][K] bf16 ----------------
__global__ __launch_bounds__(256) void transpose_cast_kernel(const float* __restrict__ src,
                                                             bf16_t* __restrict__ dst,
                                                             int K, int Ncols) {
  __shared__ float tile[32][33];
  int t = threadIdx.x;
  int tx = t & 31, ty = t >> 5;
  int bx = blockIdx.x, by = blockIdx.y;
  for (int r = ty; r < 32; r += 8)
    tile[r][tx] = src[(size_t)(by * 32 + r) * Ncols + bx * 32 + tx];
  __syncthreads();
  for (int r = ty; r < 32; r += 8)
    dst[(size_t)(bx * 32 + r) * K + by * 32 + tx] = (bf16_t)tile[tx][r];
}

// ---------------- bias gather: bias[h][i*196+j] = rpk[rel_idx[i][j]][h] ----------------
__global__ __launch_bounds__(256) void bias_gather_kernel(const float* __restrict__ rpk,
                                                          const int* __restrict__ rel_idx,
                                                          float* __restrict__ bias) {
  int pos = blockIdx.x * 256 + threadIdx.x;
  if (pos < NPOS) {
    int idx = rel_idx[pos];
    const float* r = rpk + idx * 32;
#pragma unroll
    for (int h = 0; h < 32; ++h) bias[h * NPOS + pos] = r[h];
  }
}

// ---------------- 128x128 bf16 GEMM, B^T input, K=1024, global_load_lds staging ----------------
template <int MODE>
__global__ __launch_bounds__(256, 2) void gemm_bt_kernel(
    const bf16_t* __restrict__ A, const bf16_t* __restrict__ Bt,
    bf16_t* __restrict__ qo, bf16_t* __restrict__ ko, bf16_t* __restrict__ vto,
    float* __restrict__ fo, const float* __restrict__ bp) {
  constexpr int K = 1024;
  __shared__ alignas(16) bf16_t As[128 * 32];
  __shared__ alignas(16) bf16_t Bs[128 * 32];
  const int t = threadIdx.x;
  const int lane = t & 63;
  const int quad = lane >> 4;
  const int l16 = lane & 15;
  const int wave = t >> 6;
  const int m0 = blockIdx.x * 128, n0 = blockIdx.y * 128;
  const int wr = (wave >> 1) * 64, wc = (wave & 1) * 64;

  const int c0 = t, c1 = t + 256;
  const bf16_t* gA0 = A + (size_t)(m0 + (c0 >> 2)) * K + (c0 & 3) * 8;
  const bf16_t* gA1 = A + (size_t)(m0 + (c1 >> 2)) * K + (c1 & 3) * 8;
  const bf16_t* gB0 = Bt + (size_t)(n0 + (c0 >> 2)) * K + (c0 & 3) * 8;
  const bf16_t* gB1 = Bt + (size_t)(n0 + (c1 >> 2)) * K + (c1 & 3) * 8;
  bf16_t* lA0 = As + c0 * 8;
  bf16_t* lA1 = As + c1 * 8;
  bf16_t* lB0 = Bs + c0 * 8;
  bf16_t* lB1 = Bs + c1 * 8;

  const f32x4 vzero = {0.f, 0.f, 0.f, 0.f};
  f32x4 acc[4][4];
#pragma unroll
  for (int i = 0; i < 4; ++i)
#pragma unroll
    for (int j = 0; j < 4; ++j) acc[i][j] = vzero;

  for (int kt = 0; kt < K; kt += 32) {
    __syncthreads();
    async_copy16(gA0 + kt, lA0);
    async_copy16(gA1 + kt, lA1);
    async_copy16(gB0 + kt, lB0);
    async_copy16(gB1 + kt, lB1);
    __syncthreads();
    bf16x8 af[4], bfr[4];
#pragma unroll
    for (int i = 0; i < 4; ++i) {
      af[i] = *(const bf16x8*)(As + (wr + i * 16 + l16) * 32 + quad * 8);
      bfr[i] = *(const bf16x8*)(Bs + (wc + i * 16 + l16) * 32 + quad * 8);
    }
#pragma unroll
    for (int i = 0; i < 4; ++i)
#pragma unroll
      for (int j = 0; j < 4; ++j)
        acc[i][j] = __builtin_amdgcn_mfma_f32_16x16x32_bf16(af[i], bfr[j], acc[i][j], 0, 0, 0);
  }

  if (MODE == 0) {
    const float qscale = 0.17677669529663687f;  // 1/sqrt(32)
    const int which = n0 >> 10;                 // uniform per block (1024 % 128 == 0)
#pragma unroll
    for (int i = 0; i < 4; ++i) {
      const int rb = m0 + wr + i * 16 + quad * 4;
#pragma unroll
      for (int j = 0; j < 4; ++j) {
        const int c = n0 + wc + j * 16 + l16;
        const int h = (c >> 5) & 31, d = c & 31;
#pragma unroll
        for (int r = 0; r < 4; ++r) {
          const int rg = rb + r;
          const int b = rg / 196, n = rg - b * 196;
          const float v = acc[i][j][r];
          if (which == 0)
            qo[(((size_t)b * 32 + h) * 196 + n) * 32 + d] = (bf16_t)(v * qscale);
          else if (which == 1)
            ko[(((size_t)b * 32 + h) * 196 + n) * 32 + d] = (bf16_t)v;
          else
            vto[(((size_t)b * 32 + h) * 32 + d) * 196 + n] = (bf16_t)v;
        }
      }
    }
  } else {
#pragma unroll
    for (int i = 0; i < 4; ++i) {
      const int rb = m0 + wr + i * 16 + quad * 4;
#pragma unroll
      for (int j = 0; j < 4; ++j) {
        const int c = n0 + wc + j * 16 + l16;
        const float bias_c = bp[c];
#pragma unroll
        for (int r = 0; r < 4; ++r)
          fo[(size_t)(rb + r) * 1024 + c] = acc[i][j][r] + bias_c;
      }
    }
  }
}

// ---------------- attention: one block per (b,h); wave-private, barrier-free main loop ----------------
// Each wave owns a 16-row Q chunk: scores in registers (13 f32x4 tiles), in-register
// softmax (shfl within 16-lane groups), P -> wave-private LDS (C->A layout transpose), PV.
__global__ __launch_bounds__(256, 2) void attn_kernel(
    const bf16_t* __restrict__ q, const bf16_t* __restrict__ kmat,
    const bf16_t* __restrict__ vtg, const float* __restrict__ bias,
    bf16_t* __restrict__ attn_out) {
  __shared__ alignas(16) bf16_t kf[NPAD * 32];   // K rows [n][d], rows >=196 zero
  __shared__ alignas(16) bf16_t vts[32 * NPAD];  // V^T [d][n], cols >=196 zero
  __shared__ alignas(16) bf16_t pb[4][16 * NPAD];  // per-wave unnormalized P

  const int t = threadIdx.x;
  const int lane = t & 63;
  const int quad = lane >> 4, l16 = lane & 15;
  const int wave = t >> 6;
  const int bh = blockIdx.x;
  const int b = bh >> 5, h = bh & 31;
  const bf16_t* qg = q + (size_t)bh * (196 * 32);
  const bf16_t* kg = kmat + (size_t)bh * (196 * 32);
  const bf16_t* vg = vtg + (size_t)bh * (32 * 196);
  const float* bg = bias + (size_t)h * NPOS;

  {
    const uint4* src = (const uint4*)kg;
    uint4* dst = (uint4*)kf;
    for (int c = t; c < 784; c += 256) dst[c] = src[c];   // 196*32 bf16 = 784 x 16B
    const uint4 z4 = {0u, 0u, 0u, 0u};
    for (int c = 784 + t; c < 896; c += 256) dst[c] = z4; // pad rows 196..223
    const uint2 z2 = {0u, 0u};
    for (int i = t; i < 1792; i += 256) {                 // 32 rows x 56 x 8B
      int d = i / 56, c = i - d * 56;
      uint2 val = (c < 49) ? ((const uint2*)(vg + d * 196))[c] : z2;
      ((uint2*)(vts + d * NPAD))[c] = val;
    }
  }
  __syncthreads();

  const f32x4 vzero = {0.f, 0.f, 0.f, 0.f};
  bf16_t* pw = &pb[wave][0];

  for (int ch = wave; ch < 13; ch += 4) {
    const int q0 = ch * 16;
    int qrow = q0 + l16;
    if (qrow > 195) qrow = 195;  // clamp; junk rows never stored
    const bf16x8 aq = *(const bf16x8*)(qg + qrow * 32 + quad * 8);

    f32x4 s[13];
#pragma unroll
    for (int ct = 0; ct < 13; ++ct) {
      const bf16x8 bk = *(const bf16x8*)(kf + (ct * 16 + l16) * 32 + quad * 8);
      s[ct] = __builtin_amdgcn_mfma_f32_16x16x32_bf16(aq, bk, vzero, 0, 0, 0);
    }
    // bias add + right-edge mask (C layout: row = quad*4+r, col = ct*16+l16)
#pragma unroll
    for (int ct = 0; ct < 13; ++ct) {
      const int col = ct * 16 + l16;
#pragma unroll
      for (int r = 0; r < 4; ++r) {
        int br = q0 + quad * 4 + r;
        if (br > 195) br = 195;
        if (col < 196)
          s[ct][r] += bg[br * 196 + col];
        else
          s[ct][r] = -1e30f;
      }
    }
    // row max (cols of one row live in the 16-lane group)
    float mx[4], inv[4];
#pragma unroll
    for (int r = 0; r < 4; ++r) {
      float m = s[0][r];
#pragma unroll
      for (int ct = 1; ct < 13; ++ct) m = fmaxf(m, s[ct][r]);
      m = fmaxf(m, __shfl_xor(m, 1));
      m = fmaxf(m, __shfl_xor(m, 2));
      m = fmaxf(m, __shfl_xor(m, 4));
      m = fmaxf(m, __shfl_xor(m, 8));
      mx[r] = m;
    }
#pragma unroll
    for (int ct = 0; ct < 13; ++ct)
#pragma unroll
      for (int r = 0; r < 4; ++r) s[ct][r] = __expf(s[ct][r] - mx[r]);  // masked -> 0
#pragma unroll
    for (int r = 0; r < 4; ++r) {
      float sum = s[0][r];
#pragma unroll
      for (int ct = 1; ct < 13; ++ct) sum += s[ct][r];
      sum += __shfl_xor(sum, 1);
      sum += __shfl_xor(sum, 2);
      sum += __shfl_xor(sum, 4);
      sum += __shfl_xor(sum, 8);
      inv[r] = 1.f / sum;
    }
    // P -> wave-private LDS (C layout -> memory [row][col])
#pragma unroll
    for (int ct = 0; ct < 13; ++ct) {
      const int col = ct * 16 + l16;
#pragma unroll
      for (int r = 0; r < 4; ++r) pw[(quad * 4 + r) * NPAD + col] = (bf16_t)s[ct][r];
    }
    // zero pad tile (cols 208..223): 16 rows x 16 cols, lanes 0..31 one bf16x8 each
    if (lane < 32) {
      const bf16x8 z8 = {};
      *(bf16x8*)(pw + (lane >> 1) * NPAD + 208 + (lane & 1) * 8) = z8;
    }
    // PV: same-wave LDS read-back (A layout), no barrier needed
#pragma unroll
    for (int dt = 0; dt < 2; ++dt) {
      f32x4 o = vzero;
#pragma unroll
      for (int kk = 0; kk < 7; ++kk) {
        const bf16x8 ap = *(const bf16x8*)(pw + l16 * NPAD + kk * 32 + quad * 8);
        const bf16x8 bv = *(const bf16x8*)(vts + (dt * 16 + l16) * NPAD + kk * 32 + quad * 8);
        o = __builtin_amdgcn_mfma_f32_16x16x32_bf16(ap, bv, o, 0, 0, 0);
      }
      const int d = dt * 16 + l16;
#pragma unroll
      for (int r = 0; r < 4; ++r) {
        const int n = q0 + quad * 4 + r;
        if (n < 196)
          attn_out[(((size_t)b * 196 + n) * 32 + h) * 32 + d] = (bf16_t)(o[r] * inv[r]);
      }
    }
  }
}

extern "C" void kernel_launch(void* const* d_in, const int* in_sizes, int n_in,
                              void* d_out, int out_size, void* d_ws, size_t ws_size,
                              hipStream_t stream) {
  (void)in_sizes; (void)n_in; (void)out_size; (void)ws_size;
  const float* x = (const float*)d_in[0];
  const float* Wqkv = (const float*)d_in[1];
  const float* Wproj = (const float*)d_in[2];
  const float* bproj = (const float*)d_in[3];
  const float* rpk = (const float*)d_in[4];
  const int* rel_idx = (const int*)d_in[5];
  float* out = (float*)d_out;

  char* ws = (char*)d_ws;
  bf16_t* xb = (bf16_t*)(ws + 0);                  // 25,690,112 B ; reused as attn_out
  bf16_t* wqkvT = (bf16_t*)(ws + 25690112);        //  6,291,456 B
  bf16_t* wprojT = (bf16_t*)(ws + 31981568);       //  2,097,152 B
  bf16_t* q = (bf16_t*)(ws + 34078720);            // 25,690,112 B
  bf16_t* kk = (bf16_t*)(ws + 59768832);           // 25,690,112 B
  bf16_t* vt = (bf16_t*)(ws + 85458944);           // 25,690,112 B
  float* bias = (float*)(ws + 111149056);          //  4,917,248 B  (total ~116 MB)
  bf16_t* attn = xb;                               // xb is dead after GEMM1

  cast_x_kernel<<<12544, 256, 0, stream>>>(x, xb, 12845056 / 4);
  transpose_cast_kernel<<<dim3(96, 32), 256, 0, stream>>>(Wqkv, wqkvT, 1024, 3072);
  transpose_cast_kernel<<<dim3(32, 32), 256, 0, stream>>>(Wproj, wprojT, 1024, 1024);
  bias_gather_kernel<<<151, 256, 0, stream>>>(rpk, rel_idx, bias);
  gemm_bt_kernel<0><<<dim3(98, 24), 256, 0, stream>>>(xb, wqkvT, q, kk, vt, nullptr, nullptr);
  attn_kernel<<<2048, 256, 0, stream>>>(q, kk, vt, bias, attn);
  gemm_bt_kernel<1><<<dim3(98, 8), 256, 0, stream>>>(attn, wprojT, nullptr, nullptr, nullptr, out, bproj);
}

// Round 3
// 356.385 us; speedup vs baseline: 2.2634x; 1.0523x over previous
//
#include <hip/hip_runtime.h>
#include <hip/hip_bf16.h>

typedef __bf16 bf16_t;
typedef __attribute__((ext_vector_type(8))) __bf16 bf16x8;
typedef __attribute__((ext_vector_type(4))) __bf16 bf16x4;
typedef __attribute__((ext_vector_type(4))) float f32x4;

#define NPOS 38416  // 196*196
#define NPAD 224    // 7*32
#define KSTR 40     // kf row stride (bf16): 80B = 20 banks -> 2-way (free)
#define VSTR 232    // vts/pb row stride (bf16): 464B, 16B-aligned, 2-way

__device__ __forceinline__ void async_copy16(const bf16_t* g, bf16_t* l) {
  __builtin_amdgcn_global_load_lds((const __attribute__((address_space(1))) void*)g,
                                   (__attribute__((address_space(3))) void*)l, 16, 0, 0);
}

// ---------------- cast x -> bf16 ----------------
__global__ __launch_bounds__(256) void cast_x_kernel(const float* __restrict__ x,
                                                     bf16_t* __restrict__ xb, int n4) {
  int i = blockIdx.x * 256 + threadIdx.x;
  if (i < n4) {
    float4 v = ((const float4*)x)[i];
    bf16x4 o;
    o[0] = (bf16_t)v.x; o[1] = (bf16_t)v.y; o[2] = (bf16_t)v.z; o[3] = (bf16_t)v.w;
    ((bf16x4*)xb)[i] = o;
  }
}

// ---------------- transpose + cast W: src[K][Ncols] f32 -> dst[Ncols][K] bf16 ----------------
__global__ __launch_bounds__(256) void transpose_cast_kernel(const float* __restrict__ src,
                                                             bf16_t* __restrict__ dst,
                                                             int K, int Ncols) {
  __shared__ float tile[32][33];
  int t = threadIdx.x;
  int tx = t & 31, ty = t >> 5;
  int bx = blockIdx.x, by = blockIdx.y;
  for (int r = ty; r < 32; r += 8)
    tile[r][tx] = src[(size_t)(by * 32 + r) * Ncols + bx * 32 + tx];
  __syncthreads();
  for (int r = ty; r < 32; r += 8)
    dst[(size_t)(bx * 32 + r) * K + by * 32 + tx] = (bf16_t)tile[tx][r];
}

// ---------------- bias gather: bias[h][i*196+j] = rpk[rel_idx[i][j]][h] ----------------
__global__ __launch_bounds__(256) void bias_gather_kernel(const float* __restrict__ rpk,
                                                          const int* __restrict__ rel_idx,
                                                          float* __restrict__ bias) {
  int pos = blockIdx.x * 256 + threadIdx.x;
  if (pos < NPOS) {
    int idx = rel_idx[pos];
    const float* r = rpk + idx * 32;
#pragma unroll
    for (int h = 0; h < 32; ++h) bias[h * NPOS + pos] = r[h];
  }
}

// ---------------- 128x128 bf16 GEMM, B^T input, K=1024 ----------------
// global_load_lds staging with 16B-chunk XOR swizzle (phys_chunk = glob_chunk ^ ((row>>1)&3))
// grid: (n-tiles, m-tiles) -> n fast for L2 locality (B is small; A window stays hot)
template <int MODE>
__global__ __launch_bounds__(256, 2) void gemm_bt_kernel(
    const bf16_t* __restrict__ A, const bf16_t* __restrict__ Bt,
    bf16_t* __restrict__ qo, bf16_t* __restrict__ ko, bf16_t* __restrict__ vto,
    float* __restrict__ fo, const float* __restrict__ bp) {
  constexpr int K = 1024;
  __shared__ alignas(16) bf16_t As[128 * 32];
  __shared__ alignas(16) bf16_t Bs[128 * 32];
  const int t = threadIdx.x;
  const int lane = t & 63;
  const int quad = lane >> 4;
  const int l16 = lane & 15;
  const int wave = t >> 6;
  const int m0 = blockIdx.y * 128, n0 = blockIdx.x * 128;
  const int wr = (wave >> 1) * 64, wc = (wave & 1) * 64;

  // staging: thread c fills LDS (row=c>>2, chunk=c&3); source global chunk is XOR-swizzled
  const int c0 = t, c1 = t + 256;
  const int sc0 = (c0 & 3) ^ ((c0 >> 3) & 3);
  const int sc1 = (c1 & 3) ^ ((c1 >> 3) & 3);
  const bf16_t* gA0 = A + (size_t)(m0 + (c0 >> 2)) * K + sc0 * 8;
  const bf16_t* gA1 = A + (size_t)(m0 + (c1 >> 2)) * K + sc1 * 8;
  const bf16_t* gB0 = Bt + (size_t)(n0 + (c0 >> 2)) * K + sc0 * 8;
  const bf16_t* gB1 = Bt + (size_t)(n0 + (c1 >> 2)) * K + sc1 * 8;
  bf16_t* lA0 = As + c0 * 8;
  bf16_t* lA1 = As + c1 * 8;
  bf16_t* lB0 = Bs + c0 * 8;
  bf16_t* lB1 = Bs + c1 * 8;

  // fragment reads: global chunk quad lives at phys chunk quad ^ ((l16>>1)&3)
  const int qa = quad ^ ((l16 >> 1) & 3);

  const f32x4 vzero = {0.f, 0.f, 0.f, 0.f};
  f32x4 acc[4][4];
#pragma unroll
  for (int i = 0; i < 4; ++i)
#pragma unroll
    for (int j = 0; j < 4; ++j) acc[i][j] = vzero;

  for (int kt = 0; kt < K; kt += 32) {
    __syncthreads();
    async_copy16(gA0 + kt, lA0);
    async_copy16(gA1 + kt, lA1);
    async_copy16(gB0 + kt, lB0);
    async_copy16(gB1 + kt, lB1);
    __syncthreads();
    bf16x8 af[4], bfr[4];
#pragma unroll
    for (int i = 0; i < 4; ++i) {
      af[i] = *(const bf16x8*)(As + (wr + i * 16 + l16) * 32 + qa * 8);
      bfr[i] = *(const bf16x8*)(Bs + (wc + i * 16 + l16) * 32 + qa * 8);
    }
#pragma unroll
    for (int i = 0; i < 4; ++i)
#pragma unroll
      for (int j = 0; j < 4; ++j)
        acc[i][j] = __builtin_amdgcn_mfma_f32_16x16x32_bf16(af[i], bfr[j], acc[i][j], 0, 0, 0);
  }

  if (MODE == 0) {
    const float qscale = 0.17677669529663687f;  // 1/sqrt(32)
    const int which = n0 >> 10;                 // uniform per block (1024 % 128 == 0)
#pragma unroll
    for (int i = 0; i < 4; ++i) {
      const int rb = m0 + wr + i * 16 + quad * 4;
#pragma unroll
      for (int j = 0; j < 4; ++j) {
        const int c = n0 + wc + j * 16 + l16;
        const int h = (c >> 5) & 31, d = c & 31;
#pragma unroll
        for (int r = 0; r < 4; ++r) {
          const int rg = rb + r;
          const int b = rg / 196, n = rg - b * 196;
          const float v = acc[i][j][r];
          if (which == 0)
            qo[(((size_t)b * 32 + h) * 196 + n) * 32 + d] = (bf16_t)(v * qscale);
          else if (which == 1)
            ko[(((size_t)b * 32 + h) * 196 + n) * 32 + d] = (bf16_t)v;
          else
            vto[(((size_t)b * 32 + h) * 32 + d) * 196 + n] = (bf16_t)v;
        }
      }
    }
  } else {
#pragma unroll
    for (int i = 0; i < 4; ++i) {
      const int rb = m0 + wr + i * 16 + quad * 4;
#pragma unroll
      for (int j = 0; j < 4; ++j) {
        const int c = n0 + wc + j * 16 + l16;
        const float bias_c = bp[c];
#pragma unroll
        for (int r = 0; r < 4; ++r)
          fo[(size_t)(rb + r) * 1024 + c] = acc[i][j][r] + bias_c;
      }
    }
  }
}

// ---------------- attention: one block per (b,h); wave-private, barrier-free main loop ----------------
__global__ __launch_bounds__(256, 2) void attn_kernel(
    const bf16_t* __restrict__ q, const bf16_t* __restrict__ kmat,
    const bf16_t* __restrict__ vtg, const float* __restrict__ bias,
    bf16_t* __restrict__ attn_out) {
  __shared__ alignas(16) bf16_t kf[NPAD * KSTR];    // K rows [n][d], stride 40
  __shared__ alignas(16) bf16_t vts[32 * VSTR];     // V^T [d][n], stride 232
  __shared__ alignas(16) bf16_t pb[4][16 * VSTR];   // per-wave unnormalized P

  const int t = threadIdx.x;
  const int lane = t & 63;
  const int quad = lane >> 4, l16 = lane & 15;
  const int wave = t >> 6;
  const int bh = blockIdx.x;
  const int b = bh >> 5, h = bh & 31;
  const bf16_t* qg = q + (size_t)bh * (196 * 32);
  const bf16_t* kg = kmat + (size_t)bh * (196 * 32);
  const bf16_t* vg = vtg + (size_t)bh * (32 * 196);
  const float* bg = bias + (size_t)h * NPOS;

  {
    const uint4* src = (const uint4*)kg;
    uint4* dst = (uint4*)kf;  // row r -> uint4 slots [r*5, r*5+3]; slot r*5+4 unused
    for (int c = t; c < 784; c += 256) dst[(c >> 2) * 5 + (c & 3)] = src[c];
    const uint4 z4 = {0u, 0u, 0u, 0u};
    if (t < 112) {  // zero pad rows 196..223, chunks 0..3
      int r = 196 + (t >> 2), ch = t & 3;
      dst[r * 5 + ch] = z4;
    }
    const uint2 z2 = {0u, 0u};
    for (int i = t; i < 1792; i += 256) {  // 32 rows x 56 x 8B (stride VSTR)
      int d = i / 56, c = i - d * 56;
      uint2 val = (c < 49) ? ((const uint2*)(vg + d * 196))[c] : z2;
      ((uint2*)(vts + d * VSTR))[c] = val;
    }
  }
  __syncthreads();

  const f32x4 vzero = {0.f, 0.f, 0.f, 0.f};
  bf16_t* pw = &pb[wave][0];

  for (int ch = wave; ch < 13; ch += 4) {
    const int q0 = ch * 16;
    int qrow = q0 + l16;
    if (qrow > 195) qrow = 195;  // clamp; junk rows never stored
    const bf16x8 aq = *(const bf16x8*)(qg + qrow * 32 + quad * 8);

    // prefetch bias into registers (independent of the MFMAs below)
    float bv[13][4];
#pragma unroll
    for (int ct = 0; ct < 13; ++ct) {
      const int col = ct * 16 + l16;
#pragma unroll
      for (int r = 0; r < 4; ++r) {
        int br = q0 + quad * 4 + r;
        if (br > 195) br = 195;
        bv[ct][r] = (col < 196) ? bg[br * 196 + col] : 0.f;
      }
    }

    f32x4 s[13];
#pragma unroll
    for (int ct = 0; ct < 13; ++ct) {
      const bf16x8 bk = *(const bf16x8*)(kf + (ct * 16 + l16) * KSTR + quad * 8);
      s[ct] = __builtin_amdgcn_mfma_f32_16x16x32_bf16(aq, bk, vzero, 0, 0, 0);
    }
#pragma unroll
    for (int ct = 0; ct < 13; ++ct) {
      const int col = ct * 16 + l16;
#pragma unroll
      for (int r = 0; r < 4; ++r) {
        if (col < 196)
          s[ct][r] += bv[ct][r];
        else
          s[ct][r] = -1e30f;
      }
    }
    // row max (cols of one row live in the 16-lane group)
    float mx[4], inv[4];
#pragma unroll
    for (int r = 0; r < 4; ++r) {
      float m = s[0][r];
#pragma unroll
      for (int ct = 1; ct < 13; ++ct) m = fmaxf(m, s[ct][r]);
      m = fmaxf(m, __shfl_xor(m, 1));
      m = fmaxf(m, __shfl_xor(m, 2));
      m = fmaxf(m, __shfl_xor(m, 4));
      m = fmaxf(m, __shfl_xor(m, 8));
      mx[r] = m;
    }
#pragma unroll
    for (int ct = 0; ct < 13; ++ct)
#pragma unroll
      for (int r = 0; r < 4; ++r) s[ct][r] = __expf(s[ct][r] - mx[r]);  // masked -> 0
#pragma unroll
    for (int r = 0; r < 4; ++r) {
      float sum = s[0][r];
#pragma unroll
      for (int ct = 1; ct < 13; ++ct) sum += s[ct][r];
      sum += __shfl_xor(sum, 1);
      sum += __shfl_xor(sum, 2);
      sum += __shfl_xor(sum, 4);
      sum += __shfl_xor(sum, 8);
      inv[r] = 1.f / sum;
    }
    // P -> wave-private LDS (C layout -> memory [row][col])
#pragma unroll
    for (int ct = 0; ct < 13; ++ct) {
      const int col = ct * 16 + l16;
#pragma unroll
      for (int r = 0; r < 4; ++r) pw[(quad * 4 + r) * VSTR + col] = (bf16_t)s[ct][r];
    }
    // zero pad tile (cols 208..223)
    if (lane < 32) {
      const bf16x8 z8 = {};
      *(bf16x8*)(pw + (lane >> 1) * VSTR + 208 + (lane & 1) * 8) = z8;
    }
    // PV: same-wave LDS read-back (A layout), no barrier needed
#pragma unroll
    for (int dt = 0; dt < 2; ++dt) {
      f32x4 o = vzero;
#pragma unroll
      for (int kk = 0; kk < 7; ++kk) {
        const bf16x8 ap = *(const bf16x8*)(pw + l16 * VSTR + kk * 32 + quad * 8);
        const bf16x8 bv2 = *(const bf16x8*)(vts + (dt * 16 + l16) * VSTR + kk * 32 + quad * 8);
        o = __builtin_amdgcn_mfma_f32_16x16x32_bf16(ap, bv2, o, 0, 0, 0);
      }
      const int d = dt * 16 + l16;
#pragma unroll
      for (int r = 0; r < 4; ++r) {
        const int n = q0 + quad * 4 + r;
        if (n < 196)
          attn_out[(((size_t)b * 196 + n) * 32 + h) * 32 + d] = (bf16_t)(o[r] * inv[r]);
      }
    }
  }
}

extern "C" void kernel_launch(void* const* d_in, const int* in_sizes, int n_in,
                              void* d_out, int out_size, void* d_ws, size_t ws_size,
                              hipStream_t stream) {
  (void)in_sizes; (void)n_in; (void)out_size; (void)ws_size;
  const float* x = (const float*)d_in[0];
  const float* Wqkv = (const float*)d_in[1];
  const float* Wproj = (const float*)d_in[2];
  const float* bproj = (const float*)d_in[3];
  const float* rpk = (const float*)d_in[4];
  const int* rel_idx = (const int*)d_in[5];
  float* out = (float*)d_out;

  char* ws = (char*)d_ws;
  bf16_t* xb = (bf16_t*)(ws + 0);                  // 25,690,112 B ; reused as attn_out
  bf16_t* wqkvT = (bf16_t*)(ws + 25690112);        //  6,291,456 B
  bf16_t* wprojT = (bf16_t*)(ws + 31981568);       //  2,097,152 B
  bf16_t* q = (bf16_t*)(ws + 34078720);            // 25,690,112 B
  bf16_t* kk = (bf16_t*)(ws + 59768832);           // 25,690,112 B
  bf16_t* vt = (bf16_t*)(ws + 85458944);           // 25,690,112 B
  float* bias = (float*)(ws + 111149056);          //  4,917,248 B  (total ~116 MB)
  bf16_t* attn = xb;                               // xb is dead after GEMM1

  cast_x_kernel<<<12544, 256, 0, stream>>>(x, xb, 12845056 / 4);
  transpose_cast_kernel<<<dim3(96, 32), 256, 0, stream>>>(Wqkv, wqkvT, 1024, 3072);
  transpose_cast_kernel<<<dim3(32, 32), 256, 0, stream>>>(Wproj, wprojT, 1024, 1024);
  bias_gather_kernel<<<151, 256, 0, stream>>>(rpk, rel_idx, bias);
  gemm_bt_kernel<0><<<dim3(24, 98), 256, 0, stream>>>(xb, wqkvT, q, kk, vt, nullptr, nullptr);
  attn_kernel<<<2048, 256, 0, stream>>>(q, kk, vt, bias, attn);
  gemm_bt_kernel<1><<<dim3(8, 98), 256, 0, stream>>>(attn, wprojT, nullptr, nullptr, nullptr, out, bproj);
}

// Round 4
// 348.329 us; speedup vs baseline: 2.3157x; 1.0231x over previous
//
#include <hip/hip_runtime.h>
#include <hip/hip_bf16.h>

typedef __bf16 bf16_t;
typedef __attribute__((ext_vector_type(8))) __bf16 bf16x8;
typedef __attribute__((ext_vector_type(4))) __bf16 bf16x4;
typedef __attribute__((ext_vector_type(4))) float f32x4;

#define NPOS 38416  // 196*196
#define NPAD 224    // 7*32
#define KSTR 40     // kf row stride (bf16): 80B = 20 banks -> 2-way (free)
#define VSTR 232    // vts/pb row stride (bf16): 464B, 16B-aligned, 2-way

__device__ __forceinline__ void async_copy16(const bf16_t* g, bf16_t* l) {
  __builtin_amdgcn_global_load_lds((const __attribute__((address_space(1))) void*)g,
                                   (__attribute__((address_space(3))) void*)l, 16, 0, 0);
}

// ---------------- cast x -> bf16 ----------------
__global__ __launch_bounds__(256) void cast_x_kernel(const float* __restrict__ x,
                                                     bf16_t* __restrict__ xb, int n4) {
  int i = blockIdx.x * 256 + threadIdx.x;
  if (i < n4) {
    float4 v = ((const float4*)x)[i];
    bf16x4 o;
    o[0] = (bf16_t)v.x; o[1] = (bf16_t)v.y; o[2] = (bf16_t)v.z; o[3] = (bf16_t)v.w;
    ((bf16x4*)xb)[i] = o;
  }
}

// ---------------- transpose + cast W: src[K][Ncols] f32 -> dst[Ncols][K] bf16 ----------------
__global__ __launch_bounds__(256) void transpose_cast_kernel(const float* __restrict__ src,
                                                             bf16_t* __restrict__ dst,
                                                             int K, int Ncols) {
  __shared__ float tile[32][33];
  int t = threadIdx.x;
  int tx = t & 31, ty = t >> 5;
  int bx = blockIdx.x, by = blockIdx.y;
  for (int r = ty; r < 32; r += 8)
    tile[r][tx] = src[(size_t)(by * 32 + r) * Ncols + bx * 32 + tx];
  __syncthreads();
  for (int r = ty; r < 32; r += 8)
    dst[(size_t)(bx * 32 + r) * K + by * 32 + tx] = (bf16_t)tile[tx][r];
}

// ---------------- bias gather: bias[h][i*196+j] = rpk[rel_idx[i][j]][h] ----------------
__global__ __launch_bounds__(256) void bias_gather_kernel(const float* __restrict__ rpk,
                                                          const int* __restrict__ rel_idx,
                                                          float* __restrict__ bias) {
  int pos = blockIdx.x * 256 + threadIdx.x;
  if (pos < NPOS) {
    int idx = rel_idx[pos];
    const float* r = rpk + idx * 32;
#pragma unroll
    for (int h = 0; h < 32; ++h) bias[h * NPOS + pos] = r[h];
  }
}

// ---------------- 256x128 bf16 GEMM, B^T input, K=1024 ----------------
// 512 threads / 8 waves (4x2 of 64x64). Double-buffered LDS, ONE barrier per
// K-iter: loads for tile k+1 issue right after the barrier and land during
// tile-k compute. 16B-chunk XOR swizzle (phys_chunk = glob_chunk ^ ((row>>1)&3)).
template <int MODE>
__global__ __launch_bounds__(512, 4) void gemm_bt_kernel(
    const bf16_t* __restrict__ A, const bf16_t* __restrict__ Bt,
    bf16_t* __restrict__ qo, bf16_t* __restrict__ ko, bf16_t* __restrict__ vto,
    float* __restrict__ fo, const float* __restrict__ bp) {
  constexpr int K = 1024;
  constexpr int CH = 384 * 32;  // bf16 elems per buffer: (256 A-rows + 128 B-rows) x 32
  __shared__ alignas(16) bf16_t S[2][CH];
  const int t = threadIdx.x;
  const int lane = t & 63;
  const int quad = lane >> 4;
  const int l16 = lane & 15;
  const int wave = t >> 6;
  const int m0 = blockIdx.y * 256, n0 = blockIdx.x * 128;
  const int wr = (wave >> 1) * 64, wc = (wave & 1) * 64;

  // staging: 1536 16B-chunks; thread t covers c = t, t+512, t+1024
  const bf16_t* gp[3];
  int lofs[3];
#pragma unroll
  for (int j = 0; j < 3; ++j) {
    const int c = t + j * 512;
    const int row = c >> 2;
    const int sc = (c & 3) ^ ((c >> 3) & 3);
    gp[j] = (row < 256) ? A + (size_t)(m0 + row) * K + sc * 8
                        : Bt + (size_t)(n0 + row - 256) * K + sc * 8;
    lofs[j] = c * 8;
  }

  // fragment reads: global chunk `quad` lives at phys chunk quad ^ ((l16>>1)&3)
  const int qa = quad ^ ((l16 >> 1) & 3);

  const f32x4 vzero = {0.f, 0.f, 0.f, 0.f};
  f32x4 acc[4][4];
#pragma unroll
  for (int i = 0; i < 4; ++i)
#pragma unroll
    for (int j = 0; j < 4; ++j) acc[i][j] = vzero;

  // preload k-tile 0 into S[0]
#pragma unroll
  for (int j = 0; j < 3; ++j) async_copy16(gp[j], &S[0][lofs[j]]);

  for (int it = 0; it < K / 32; ++it) {
    __syncthreads();  // drains loads issued one full iteration ago
    const bf16_t* Sb = S[it & 1];
    if (it + 1 < K / 32) {
      bf16_t* Sn = S[(it + 1) & 1];
      const int kt = (it + 1) * 32;
#pragma unroll
      for (int j = 0; j < 3; ++j) async_copy16(gp[j] + kt, Sn + lofs[j]);
    }
    const bf16_t* As = Sb;
    const bf16_t* Bs = Sb + 256 * 32;
    bf16x8 af[4], bfr[4];
#pragma unroll
    for (int i = 0; i < 4; ++i) {
      af[i] = *(const bf16x8*)(As + (wr + i * 16 + l16) * 32 + qa * 8);
      bfr[i] = *(const bf16x8*)(Bs + (wc + i * 16 + l16) * 32 + qa * 8);
    }
#pragma unroll
    for (int i = 0; i < 4; ++i)
#pragma unroll
      for (int j = 0; j < 4; ++j)
        acc[i][j] = __builtin_amdgcn_mfma_f32_16x16x32_bf16(af[i], bfr[j], acc[i][j], 0, 0, 0);
  }

  if (MODE == 0) {
    const float qscale = 0.17677669529663687f;  // 1/sqrt(32)
    const int which = n0 >> 10;                 // uniform per block (1024 % 128 == 0)
#pragma unroll
    for (int i = 0; i < 4; ++i) {
      const int rb = m0 + wr + i * 16 + quad * 4;
#pragma unroll
      for (int j = 0; j < 4; ++j) {
        const int c = n0 + wc + j * 16 + l16;
        const int h = (c >> 5) & 31, d = c & 31;
#pragma unroll
        for (int r = 0; r < 4; ++r) {
          const int rg = rb + r;
          const int b = rg / 196, n = rg - b * 196;
          const float v = acc[i][j][r];
          if (which == 0)
            qo[(((size_t)b * 32 + h) * 196 + n) * 32 + d] = (bf16_t)(v * qscale);
          else if (which == 1)
            ko[(((size_t)b * 32 + h) * 196 + n) * 32 + d] = (bf16_t)v;
          else
            vto[(((size_t)b * 32 + h) * 32 + d) * 196 + n] = (bf16_t)v;
        }
      }
    }
  } else {
#pragma unroll
    for (int i = 0; i < 4; ++i) {
      const int rb = m0 + wr + i * 16 + quad * 4;
#pragma unroll
      for (int j = 0; j < 4; ++j) {
        const int c = n0 + wc + j * 16 + l16;
        const float bias_c = bp[c];
#pragma unroll
        for (int r = 0; r < 4; ++r)
          fo[(size_t)(rb + r) * 1024 + c] = acc[i][j][r] + bias_c;
      }
    }
  }
}

// ---------------- attention: one block per (b,h); wave-private, barrier-free main loop ----------------
__global__ __launch_bounds__(256, 2) void attn_kernel(
    const bf16_t* __restrict__ q, const bf16_t* __restrict__ kmat,
    const bf16_t* __restrict__ vtg, const float* __restrict__ bias,
    bf16_t* __restrict__ attn_out) {
  __shared__ alignas(16) bf16_t kf[NPAD * KSTR];    // K rows [n][d], stride 40
  __shared__ alignas(16) bf16_t vts[32 * VSTR];     // V^T [d][n], stride 232
  __shared__ alignas(16) bf16_t pb[4][16 * VSTR];   // per-wave unnormalized P

  const int t = threadIdx.x;
  const int lane = t & 63;
  const int quad = lane >> 4, l16 = lane & 15;
  const int wave = t >> 6;
  const int bh = blockIdx.x;
  const int b = bh >> 5, h = bh & 31;
  const bf16_t* qg = q + (size_t)bh * (196 * 32);
  const bf16_t* kg = kmat + (size_t)bh * (196 * 32);
  const bf16_t* vg = vtg + (size_t)bh * (32 * 196);
  const float* bg = bias + (size_t)h * NPOS;

  {
    const uint4* src = (const uint4*)kg;
    uint4* dst = (uint4*)kf;  // row r -> uint4 slots [r*5, r*5+3]; slot r*5+4 unused
    for (int c = t; c < 784; c += 256) dst[(c >> 2) * 5 + (c & 3)] = src[c];
    const uint4 z4 = {0u, 0u, 0u, 0u};
    if (t < 112) {  // zero pad rows 196..223, chunks 0..3
      int r = 196 + (t >> 2), ch = t & 3;
      dst[r * 5 + ch] = z4;
    }
    const uint2 z2 = {0u, 0u};
    for (int i = t; i < 1792; i += 256) {  // 32 rows x 56 x 8B (stride VSTR)
      int d = i / 56, c = i - d * 56;
      uint2 val = (c < 49) ? ((const uint2*)(vg + d * 196))[c] : z2;
      ((uint2*)(vts + d * VSTR))[c] = val;
    }
  }
  __syncthreads();

  const f32x4 vzero = {0.f, 0.f, 0.f, 0.f};
  bf16_t* pw = &pb[wave][0];

  for (int ch = wave; ch < 13; ch += 4) {
    const int q0 = ch * 16;
    int qrow = q0 + l16;
    if (qrow > 195) qrow = 195;  // clamp; junk rows never stored
    const bf16x8 aq = *(const bf16x8*)(qg + qrow * 32 + quad * 8);

    // prefetch bias into registers (independent of the MFMAs below)
    float bv[13][4];
#pragma unroll
    for (int ct = 0; ct < 13; ++ct) {
      const int col = ct * 16 + l16;
#pragma unroll
      for (int r = 0; r < 4; ++r) {
        int br = q0 + quad * 4 + r;
        if (br > 195) br = 195;
        bv[ct][r] = (col < 196) ? bg[br * 196 + col] : 0.f;
      }
    }

    f32x4 s[13];
#pragma unroll
    for (int ct = 0; ct < 13; ++ct) {
      const bf16x8 bk = *(const bf16x8*)(kf + (ct * 16 + l16) * KSTR + quad * 8);
      s[ct] = __builtin_amdgcn_mfma_f32_16x16x32_bf16(aq, bk, vzero, 0, 0, 0);
    }
#pragma unroll
    for (int ct = 0; ct < 13; ++ct) {
      const int col = ct * 16 + l16;
#pragma unroll
      for (int r = 0; r < 4; ++r) {
        if (col < 196)
          s[ct][r] += bv[ct][r];
        else
          s[ct][r] = -1e30f;
      }
    }
    // row max (cols of one row live in the 16-lane group)
    float mx[4], inv[4];
#pragma unroll
    for (int r = 0; r < 4; ++r) {
      float m = s[0][r];
#pragma unroll
      for (int ct = 1; ct < 13; ++ct) m = fmaxf(m, s[ct][r]);
      m = fmaxf(m, __shfl_xor(m, 1));
      m = fmaxf(m, __shfl_xor(m, 2));
      m = fmaxf(m, __shfl_xor(m, 4));
      m = fmaxf(m, __shfl_xor(m, 8));
      mx[r] = m;
    }
#pragma unroll
    for (int ct = 0; ct < 13; ++ct)
#pragma unroll
      for (int r = 0; r < 4; ++r) s[ct][r] = __expf(s[ct][r] - mx[r]);  // masked -> 0
#pragma unroll
    for (int r = 0; r < 4; ++r) {
      float sum = s[0][r];
#pragma unroll
      for (int ct = 1; ct < 13; ++ct) sum += s[ct][r];
      sum += __shfl_xor(sum, 1);
      sum += __shfl_xor(sum, 2);
      sum += __shfl_xor(sum, 4);
      sum += __shfl_xor(sum, 8);
      inv[r] = 1.f / sum;
    }
    // P -> wave-private LDS (C layout -> memory [row][col])
#pragma unroll
    for (int ct = 0; ct < 13; ++ct) {
      const int col = ct * 16 + l16;
#pragma unroll
      for (int r = 0; r < 4; ++r) pw[(quad * 4 + r) * VSTR + col] = (bf16_t)s[ct][r];
    }
    // zero pad tile (cols 208..223)
    if (lane < 32) {
      const bf16x8 z8 = {};
      *(bf16x8*)(pw + (lane >> 1) * VSTR + 208 + (lane & 1) * 8) = z8;
    }
    // PV: same-wave LDS read-back (A layout), no barrier needed
#pragma unroll
    for (int dt = 0; dt < 2; ++dt) {
      f32x4 o = vzero;
#pragma unroll
      for (int kk = 0; kk < 7; ++kk) {
        const bf16x8 ap = *(const bf16x8*)(pw + l16 * VSTR + kk * 32 + quad * 8);
        const bf16x8 bv2 = *(const bf16x8*)(vts + (dt * 16 + l16) * VSTR + kk * 32 + quad * 8);
        o = __builtin_amdgcn_mfma_f32_16x16x32_bf16(ap, bv2, o, 0, 0, 0);
      }
      const int d = dt * 16 + l16;
#pragma unroll
      for (int r = 0; r < 4; ++r) {
        const int n = q0 + quad * 4 + r;
        if (n < 196)
          attn_out[(((size_t)b * 196 + n) * 32 + h) * 32 + d] = (bf16_t)(o[r] * inv[r]);
      }
    }
  }
}

extern "C" void kernel_launch(void* const* d_in, const int* in_sizes, int n_in,
                              void* d_out, int out_size, void* d_ws, size_t ws_size,
                              hipStream_t stream) {
  (void)in_sizes; (void)n_in; (void)out_size; (void)ws_size;
  const float* x = (const float*)d_in[0];
  const float* Wqkv = (const float*)d_in[1];
  const float* Wproj = (const float*)d_in[2];
  const float* bproj = (const float*)d_in[3];
  const float* rpk = (const float*)d_in[4];
  const int* rel_idx = (const int*)d_in[5];
  float* out = (float*)d_out;

  char* ws = (char*)d_ws;
  bf16_t* xb = (bf16_t*)(ws + 0);                  // 25,690,112 B ; reused as attn_out
  bf16_t* wqkvT = (bf16_t*)(ws + 25690112);        //  6,291,456 B
  bf16_t* wprojT = (bf16_t*)(ws + 31981568);       //  2,097,152 B
  bf16_t* q = (bf16_t*)(ws + 34078720);            // 25,690,112 B
  bf16_t* kk = (bf16_t*)(ws + 59768832);           // 25,690,112 B
  bf16_t* vt = (bf16_t*)(ws + 85458944);           // 25,690,112 B
  float* bias = (float*)(ws + 111149056);          //  4,917,248 B  (total ~116 MB)
  bf16_t* attn = xb;                               // xb is dead after GEMM1

  cast_x_kernel<<<12544, 256, 0, stream>>>(x, xb, 12845056 / 4);
  transpose_cast_kernel<<<dim3(96, 32), 256, 0, stream>>>(Wqkv, wqkvT, 1024, 3072);
  transpose_cast_kernel<<<dim3(32, 32), 256, 0, stream>>>(Wproj, wprojT, 1024, 1024);
  bias_gather_kernel<<<151, 256, 0, stream>>>(rpk, rel_idx, bias);
  gemm_bt_kernel<0><<<dim3(24, 49), 512, 0, stream>>>(xb, wqkvT, q, kk, vt, nullptr, nullptr);
  attn_kernel<<<2048, 256, 0, stream>>>(q, kk, vt, bias, attn);
  gemm_bt_kernel<1><<<dim3(8, 49), 512, 0, stream>>>(attn, wprojT, nullptr, nullptr, nullptr, out, bproj);
}